// Round 14
// baseline (108.604 us; speedup 1.0000x reference)
//
#include <hip/hip_runtime.h>

// eTofts model: B=8, T=60, H=W=256.  DIAGNOSTIC ROUND.
// Dispatch 1 = R11 verbatim (best, 31.1 us): correct output.
// Dispatch 2 = same kernel x3 repeat -> d_ws (~95 us): finally shows OUR
// kernel's counters (VALUBusy / FETCH / WRITE) in the top-5 table.
// Discriminator: VALUBusy>70% => compute-bound, attack math chain.
//                VALUBusy<40% => mixed-stream memory ceiling, declare R11.

#define N_TIME 60
#define HW (256 * 256)
#define TPB 256
#define GRID 512                     // 2 blocks/CU -> 8 waves/CU

typedef float f32x4 __attribute__((ext_vector_type(4)));

template <int REPS>
__device__ __forceinline__ void etofts_body(
    const float* __restrict__ params,
    const float* __restrict__ Cp,
    const float* __restrict__ S0,
    const float* __restrict__ T1,
    float* __restrict__ out)
{
    const float DT     = 5.0f;
    const float TR     = 5.0f;
    const float EPS    = 1e-8f;
    const float COS_FA = 0.9848077530122081f;            // cos(10 deg)
    const float QC2    = 0.0225f * 1.4426950408889634f;  // (R1*TR/1000)*log2(e)

    const int bx  = blockIdx.x;
    const int b   = bx >> 6;
    const int blk = bx & 63;

    const int w    = threadIdx.x >> 6;
    const int lane = threadIdx.x & 63;
    const int pixw = blk * 1024 + w * 256 + lane * 4;

    const size_t plane = (size_t)b * HW + pixw;

    const float4 kt4 = *reinterpret_cast<const float4*>(params + ((size_t)b * 3 + 0) * HW + pixw);
    const float4 vp4 = *reinterpret_cast<const float4*>(params + ((size_t)b * 3 + 1) * HW + pixw);
    const float4 ve4 = *reinterpret_cast<const float4*>(params + ((size_t)b * 3 + 2) * HW + pixw);
    const float4 s04 = *reinterpret_cast<const float4*>(S0 + plane);
    const float4 t14 = *reinterpret_cast<const float4*>(T1 + plane);

    float Kt[4], vp[4], decay[4], Ce[4], eP[4], Kc[4], d0[4], d1[4];
    {
        const float ktv[4] = {kt4.x, kt4.y, kt4.z, kt4.w};
        const float vpv[4] = {vp4.x, vp4.y, vp4.z, vp4.w};
        const float vev[4] = {ve4.x, ve4.y, ve4.z, ve4.w};
        const float s0v[4] = {s04.x, s04.y, s04.z, s04.w};
        const float t1v[4] = {t14.x, t14.y, t14.z, t14.w};
#pragma unroll
        for (int i = 0; i < 4; ++i) {
            const float Ktrans = ktv[i] * (1.0f / 60.0f);
            const float Kep    = __fdividef(Ktrans, vev[i] + EPS);
            Kt[i]    = Ktrans;
            vp[i]    = vpv[i];
            decay[i] = __expf(-Kep * DT);
            const float P = __fdividef(TR, t1v[i] + EPS);
            const float e = __expf(-P);
            eP[i] = e;
            Kc[i] = (1.0f - COS_FA * e) * s0v[i];
            const float den1 = 1.0f - e;
            d0[i] = den1 + EPS;
            d1[i] = COS_FA * den1;
            Ce[i] = 0.0f;
        }
    }

    const float* cp_row = Cp + b * N_TIME;
    float* outp = out + ((size_t)b * N_TIME) * HW + pixw;

    for (int r = 0; r < REPS; ++r) {
        float Ce2[4];
#pragma unroll
        for (int i = 0; i < 4; ++i) Ce2[i] = Ce[i];
#pragma unroll 4
        for (int t = 0; t < N_TIME; ++t) {
            const float cp   = cp_row[t];
            const float cpdt = cp * DT;
            float st[4];
#pragma unroll
            for (int i = 0; i < 4; ++i) {
                Ce2[i] = Ce2[i] * decay[i] + cpdt;
                const float Ct  = vp[i] * cp + Kt[i] * Ce2[i];
                const float ePQ = eP[i] * exp2f(-QC2 * Ct);
                const float num = Kc[i] - Kc[i] * ePQ;
                const float den = d0[i] - d1[i] * ePQ;
                st[i] = __fdividef(num, den);
            }
            f32x4 v = {st[0], st[1], st[2], st[3]};
            __builtin_nontemporal_store(v, reinterpret_cast<f32x4*>(outp + (size_t)t * HW));
        }
    }
}

__global__ __launch_bounds__(TPB) void etofts_kernel(
    const float* __restrict__ params, const float* __restrict__ Cp,
    const float* __restrict__ S0, const float* __restrict__ T1,
    float* __restrict__ out)
{
    etofts_body<1>(params, Cp, S0, T1, out);
}

__global__ __launch_bounds__(TPB) void etofts_probe(
    const float* __restrict__ params, const float* __restrict__ Cp,
    const float* __restrict__ S0, const float* __restrict__ T1,
    float* __restrict__ ws)
{
    etofts_body<3>(params, Cp, S0, T1, ws);
}

extern "C" void kernel_launch(void* const* d_in, const int* in_sizes, int n_in,
                              void* d_out, int out_size, void* d_ws, size_t ws_size,
                              hipStream_t stream) {
    const float* params = (const float*)d_in[0];
    const float* Cp     = (const float*)d_in[1];
    const float* S0     = (const float*)d_in[2];
    const float* T1     = (const float*)d_in[3];
    float* out          = (float*)d_out;

    etofts_kernel<<<GRID, TPB, 0, stream>>>(params, Cp, S0, T1, out);

    // Diagnostic probe: same access pattern, x3 duration, writes to d_ws so
    // it appears in the rocprof top-5 with its own VALUBusy/FETCH/WRITE.
    const size_t need = (size_t)8 * N_TIME * HW * sizeof(float);  // 126 MB
    if (ws_size >= need) {
        etofts_probe<<<GRID, TPB, 0, stream>>>(params, Cp, S0, T1, (float*)d_ws);
    }
}

// Round 15
// 27.561 us; speedup vs baseline: 3.9404x; 3.9404x over previous
//
#include <hip/hip_runtime.h>

// eTofts model: B=8, T=60, H=W=256.
//   params[B,3,H,W], Cp[B,T], S0[B,1,H,W], T1[B,1,H,W] -> St[B,T,H,W] fp32
//
// R14 diagnostic (probe with own counters): VALUBusy 80-82%, hbm 4.4 TB/s
// (54%) => COMPUTE/ISSUE-bound, not memory-bound. exp2f = OCML safe exp2
// (multi-inst fixups), not bare v_exp_f32. R15: single-inst transcendentals
// (inline asm v_exp_f32 / v_rcp_f32) + algebraic fusion:
//   ePQ = exp2(F - QC2*Ct), F = -P*log2e  (eP folded into exponent)
//   St  = A + Bc * rcp(den), den = fma(nd1, u, d0)   (partial fractions)
// => 4 fma + exp + rcp per element. Geometry = R11 (best, 31.1 us):
// 512 blocks, 4 px/thread, 1 KB nt stores, scalar Cp, inputs read once.

#define N_TIME 60
#define HW (256 * 256)
#define TPB 256
#define GRID 512                     // 2 blocks/CU -> 8 waves/CU

typedef float f32x4 __attribute__((ext_vector_type(4)));

__device__ __forceinline__ float fexp2(float x) {
    float r;
    asm("v_exp_f32 %0, %1" : "=v"(r) : "v"(x));
    return r;
}
__device__ __forceinline__ float frcp(float x) {
    float r;
    asm("v_rcp_f32 %0, %1" : "=v"(r) : "v"(x));
    return r;
}

__global__ __launch_bounds__(TPB) void etofts_kernel(
    const float* __restrict__ params,  // [B,3,H,W]
    const float* __restrict__ Cp,      // [B,T]
    const float* __restrict__ S0,      // [B,1,H,W]
    const float* __restrict__ T1,      // [B,1,H,W]
    float* __restrict__ out)           // [B,T,H,W]
{
    const float DT     = 5.0f;
    const float TR     = 5.0f;
    const float EPS    = 1e-8f;
    const float COS_FA = 0.9848077530122081f;            // cos(10 deg)
    const float LOG2E  = 1.4426950408889634f;
    const float QC2    = 0.0225f * LOG2E;                // (R1*TR/1000)*log2e

    // 512 blocks: 64 per batch. Block-uniform -> Cp is scalar s_load.
    const int bx  = blockIdx.x;
    const int b   = bx >> 6;
    const int blk = bx & 63;

    // Wave w writes one 1 KB contiguous span per frame.
    const int w    = threadIdx.x >> 6;
    const int lane = threadIdx.x & 63;
    const int pixw = blk * 1024 + w * 256 + lane * 4;

    const size_t plane = (size_t)b * HW + pixw;

    const float4 kt4 = *reinterpret_cast<const float4*>(params + ((size_t)b * 3 + 0) * HW + pixw);
    const float4 vp4 = *reinterpret_cast<const float4*>(params + ((size_t)b * 3 + 1) * HW + pixw);
    const float4 ve4 = *reinterpret_cast<const float4*>(params + ((size_t)b * 3 + 2) * HW + pixw);
    const float4 s04 = *reinterpret_cast<const float4*>(S0 + plane);
    const float4 t14 = *reinterpret_cast<const float4*>(T1 + plane);

    // Per-pixel loop constants:
    //  Ce recurrence: Ce = fma(Ce, decay, cp*DT)
    //  exponent:      E  = fma(G, Ce, fma(nQv, cp, F)),  u = exp2(E)
    //  signal:        den = fma(nd1, u, d0),  St = fma(Bc, rcp(den), A)
    float decay[4], G[4], nQv[4], F[4], d0[4], nd1[4], A[4], Bc[4], Ce[4];
    {
        const float ktv[4] = {kt4.x, kt4.y, kt4.z, kt4.w};
        const float vpv[4] = {vp4.x, vp4.y, vp4.z, vp4.w};
        const float vev[4] = {ve4.x, ve4.y, ve4.z, ve4.w};
        const float s0v[4] = {s04.x, s04.y, s04.z, s04.w};
        const float t1v[4] = {t14.x, t14.y, t14.z, t14.w};
#pragma unroll
        for (int i = 0; i < 4; ++i) {
            const float Ktrans = ktv[i] * (1.0f / 60.0f);
            const float Kep    = __fdividef(Ktrans, vev[i] + EPS);
            decay[i] = __expf(-Kep * DT);
            const float P  = __fdividef(TR, t1v[i] + EPS);
            const float eP = __expf(-P);
            G[i]   = -QC2 * Ktrans;
            nQv[i] = -QC2 * vpv[i];
            F[i]   = -P * LOG2E;
            const float Kc   = (1.0f - COS_FA * eP) * s0v[i];
            const float den1 = 1.0f - eP;
            const float dd0  = den1 + EPS;
            const float dd1  = COS_FA * den1;
            d0[i]  = dd0;
            nd1[i] = -dd1;
            A[i]   = Kc / dd1;
            Bc[i]  = Kc * (dd1 - dd0) / dd1;
            Ce[i]  = 0.0f;
        }
    }

    const float* cp_row = Cp + b * N_TIME;   // uniform -> scalar s_load
    float* outp = out + ((size_t)b * N_TIME) * HW + pixw;

#pragma unroll 4
    for (int t = 0; t < N_TIME; ++t) {
        const float cp   = cp_row[t];
        const float cpdt = cp * DT;
        float st[4];
#pragma unroll
        for (int i = 0; i < 4; ++i) {
            Ce[i] = __builtin_fmaf(Ce[i], decay[i], cpdt);
            const float E   = __builtin_fmaf(G[i], Ce[i],
                              __builtin_fmaf(nQv[i], cp, F[i]));
            const float u   = fexp2(E);
            const float den = __builtin_fmaf(nd1[i], u, d0[i]);
            st[i] = __builtin_fmaf(Bc[i], frcp(den), A[i]);
        }
        f32x4 v = {st[0], st[1], st[2], st[3]};
        __builtin_nontemporal_store(v, reinterpret_cast<f32x4*>(outp + (size_t)t * HW));
    }
}

extern "C" void kernel_launch(void* const* d_in, const int* in_sizes, int n_in,
                              void* d_out, int out_size, void* d_ws, size_t ws_size,
                              hipStream_t stream) {
    const float* params = (const float*)d_in[0];
    const float* Cp     = (const float*)d_in[1];
    const float* S0     = (const float*)d_in[2];
    const float* T1     = (const float*)d_in[3];
    float* out          = (float*)d_out;

    etofts_kernel<<<GRID, TPB, 0, stream>>>(params, Cp, S0, T1, out);
}